// Round 1
// baseline (492.010 us; speedup 1.0000x reference)
//
#include <hip/hip_runtime.h>
#include <hip/hip_cooperative_groups.h>

namespace cg = cooperative_groups;

// Problem constants
constexpr int Bc  = 4;
constexpr int Sc  = 384;
constexpr int Dc  = 300;
constexpr int Ec  = 50;
constexpr int HDc = 150;          // D / L
constexpr int WHC = 350;          // Wh row length
constexpr int MT  = Bc * Sc;      // 1536

typedef __attribute__((ext_vector_type(8))) short bf16x8;
typedef __attribute__((ext_vector_type(4))) float f32x4;

__device__ __forceinline__ short f2bf(float x) {
    union { float f; unsigned u; } v; v.f = x;
    unsigned r = (v.u + 0x7FFFu + ((v.u >> 16) & 1u)) >> 16;
    return (short)r;
}

// ---------------------------------------------------------------------------
// Device bodies — identical math to the verified kernels; shared by the
// cooperative mega-kernel and the multi-launch fallback path.
// ---------------------------------------------------------------------------

// 64-row adj tile: A0[g] = (sum_e adj[g,:])/E ; wadj[g] = sum_e adj[g,e]*we[e]
__device__ __forceinline__ void reduce_unit(
    float* tile, const float* wec,
    const float* __restrict__ adj,
    float* __restrict__ A0, float* __restrict__ wadj, int unit)
{
    int t = threadIdx.x;
    __syncthreads();                 // protect LDS reuse from previous unit
    long base = (long)unit * 3200;   // 64 rows * 50 floats
    const float4* p4 = (const float4*)(adj + base);
    float4 v0 = p4[t];
    float4 v1 = p4[t + 256];
    float4 v2 = p4[t + 512];
    float4 v3 = {0.f, 0.f, 0.f, 0.f};
    if (t < 32) v3 = p4[t + 768];

    auto scat = [&](int i, const float4& v) {
        const float* vp = (const float*)&v;
        #pragma unroll
        for (int j = 0; j < 4; ++j) {
            int e = 4 * i + j;
            tile[(e / 50) * 51 + (e % 50)] = vp[j];
        }
    };
    scat(t, v0);
    scat(t + 256, v1);
    scat(t + 512, v2);
    if (t < 32) scat(t + 768, v3);
    __syncthreads();

    int r = t >> 2, q = t & 3;
    int h0 = q * 13, h1 = (q == 3) ? 50 : h0 + 13;
    const float* row = tile + r * 51;
    float s = 0.f, w = 0.f;
    for (int i = h0; i < h1; ++i) { float v = row[i]; s += v; w += v * wec[i]; }
    s += __shfl_xor(s, 1); w += __shfl_xor(w, 1);
    s += __shfl_xor(s, 2); w += __shfl_xor(w, 2);
    if (q == 0) {
        int g = unit * 64 + r;
        A0[g]   = s * (1.0f / Ec);
        wadj[g] = w;
    }
}

// wave per row: s12[2g] = G0[g]·w1cs, s12[2g+1] = G0[g]·w2cs
__device__ __forceinline__ void s12_unit(const float* __restrict__ G,
                                         const float* __restrict__ sm,
                                         float* __restrict__ s12, int unit)
{
    int wave = threadIdx.x >> 6, lane = threadIdx.x & 63;
    int g = unit * 4 + wave;
    const float* gp = G + (long)g * Dc;
    float a = 0.f, c = 0.f;
    #pragma unroll
    for (int h0 = 0; h0 < HDc; h0 += 64) {
        int h = h0 + lane;
        if (h < HDc) { float v = gp[h]; a += v * sm[64 + h]; c += v * sm[224 + h]; }
    }
    #pragma unroll
    for (int off = 32; off; off >>= 1) {
        a += __shfl_down(a, off);
        c += __shfl_down(c, off);
    }
    if (lane == 0) { s12[2*g] = a; s12[2*g + 1] = c; }
}

// bf16 MFMA GEMM body, 256 thr = 4 waves, 32x32 C tile, BK=64.
template<int BSRC, int A1M, int HASD, int HASB, int RELU>
__device__ __forceinline__ void mgemm_body(
    short* As, short* Bs, int bx, int by, int b,
    const float* __restrict__ A, int lda, long sA,
    const float* __restrict__ Bw, int ldb, long sB,
    const float* __restrict__ W1a, const float* __restrict__ WoutP,
    const float* __restrict__ Dm, int ldd, long sD,
    const float* __restrict__ bias, float bscale,
    const float* __restrict__ s12, const float* __restrict__ sm,
    float* __restrict__ C, int ldc, long sC,
    int M, int N, int K)
{
    const float* Ap = A + (long)b * sA;
    const float* Bp = Bw + (long)b * sB;
    const float* Dp = Dm + (long)b * sD;
    float* Cp = C + (long)b * sC;

    const int tid  = threadIdx.x;
    const int wave = tid >> 6, lane = tid & 63;
    const int wm = wave & 1, wn = wave >> 1;
    const int lm = lane & 15, quad = lane >> 4;
    const int m0 = by * 32, n0 = bx * 32;

    const int srow = tid >> 3;           // 0..31 (A rows / B n-rows)
    const int sk   = (tid & 7) * 8;      // 0,8,..,56
    const int nc   = tid & 31;           // BSRC0 n
    const int kr   = tid >> 5;           // BSRC0 k base 0..7

    float sbh = 0.f; const float* s1p = nullptr; float s2v = 0.f;
    if constexpr (A1M) {
        sbh = sm[384];
        s1p = s12 + 2L * Sc * b;
        s2v = s1p[2 * (m0 + srow) + 1];
    }

    float ra[8], rb[8];

    auto stageA = [&](int k0) {
        int am = m0 + srow;
        int kb = k0 + sk;
        if constexpr (A1M) {             // K=384 exact, no masks
            float4 u = *(const float4*)(Ap + (long)am * lda + kb);
            float4 w = *(const float4*)(Ap + (long)am * lda + kb + 4);
            const float* up = (const float*)&u;
            const float* wp = (const float*)&w;
            #pragma unroll
            for (int j = 0; j < 4; ++j) {
                ra[j]     = (up[j] + s1p[2*(kb + j)]     + s2v + sbh) * (1.0f/Ec);
                ra[4 + j] = (wp[j] + s1p[2*(kb + 4 + j)] + s2v + sbh) * (1.0f/Ec);
            }
        } else {
            if (kb + 7 < K) {
                float4 u = *(const float4*)(Ap + (long)am * lda + kb);
                float4 w = *(const float4*)(Ap + (long)am * lda + kb + 4);
                ra[0]=u.x; ra[1]=u.y; ra[2]=u.z; ra[3]=u.w;
                ra[4]=w.x; ra[5]=w.y; ra[6]=w.z; ra[7]=w.w;
            } else {
                #pragma unroll
                for (int j = 0; j < 8; ++j) {
                    int k = kb + j;
                    ra[j] = (k < K) ? Ap[(long)am * lda + k] : 0.f;
                }
            }
        }
    };

    auto stageB = [&](int k0) {
        if constexpr (BSRC == 0) {       // k-major, K=384 exact here
            int n = n0 + nc;
            bool nok = n < N;
            #pragma unroll
            for (int p = 0; p < 8; ++p) {
                int k = k0 + kr + p * 8;
                rb[p] = nok ? Bp[(long)k * ldb + n] : 0.f;
            }
        } else {
            int nr = n0 + srow;
            bool nok = nr < N;
            const float* wp = Bp; int ld = ldb; int nn = nr;
            if constexpr (BSRC == 2) {
                if (nr < 150)      { wp = Bp;    ld = 300; nn = nr; }
                else if (nr < 300) { wp = W1a;   ld = 450; nn = nr - 150; }
                else               { wp = WoutP; ld = 300; nn = nr - 300; }
            }
            #pragma unroll
            for (int p = 0; p < 4; ++p) {
                int k = k0 + sk + 2 * p;
                if (nok && k + 1 < K) {
                    float2 v = *(const float2*)(wp + (long)nn * ld + k);
                    rb[2*p] = v.x; rb[2*p + 1] = v.y;
                } else {
                    rb[2*p]     = (nok && k < K)     ? wp[(long)nn * ld + k]     : 0.f;
                    rb[2*p + 1] = (nok && k + 1 < K) ? wp[(long)nn * ld + k + 1] : 0.f;
                }
            }
        }
    };

    auto stash = [&]() {
        #pragma unroll
        for (int j = 0; j < 8; ++j) As[srow * 72 + sk + j] = f2bf(ra[j]);
        if constexpr (BSRC == 0) {
            #pragma unroll
            for (int p = 0; p < 8; ++p) Bs[nc * 72 + kr + p * 8] = f2bf(rb[p]);
        } else {
            #pragma unroll
            for (int j = 0; j < 8; ++j) Bs[srow * 72 + sk + j] = f2bf(rb[j]);
        }
    };

    f32x4 acc = {0.f, 0.f, 0.f, 0.f};

    stageA(0); stageB(0);
    for (int k0 = 0; k0 < K; k0 += 64) {
        __syncthreads();
        stash();
        __syncthreads();
        if (k0 + 64 < K) { stageA(k0 + 64); stageB(k0 + 64); }
        {
            bf16x8 a0 = *(const bf16x8*)(As + (wm*16 + lm) * 72 + quad * 8);
            bf16x8 b0 = *(const bf16x8*)(Bs + (wn*16 + lm) * 72 + quad * 8);
            acc = __builtin_amdgcn_mfma_f32_16x16x32_bf16(a0, b0, acc, 0, 0, 0);
            bf16x8 a1 = *(const bf16x8*)(As + (wm*16 + lm) * 72 + 32 + quad * 8);
            bf16x8 b1 = *(const bf16x8*)(Bs + (wn*16 + lm) * 72 + 32 + quad * 8);
            acc = __builtin_amdgcn_mfma_f32_16x16x32_bf16(a1, b1, acc, 0, 0, 0);
        }
    }

    int cn = n0 + wn * 16 + lm;
    if (cn < N) {
        #pragma unroll
        for (int r = 0; r < 4; ++r) {
            int cm = m0 + wm * 16 + quad * 4 + r;
            if (cm < M) {
                float v = acc[r];
                if constexpr (HASD) v += Dp[(long)cm * ldd + cn];
                if constexpr (HASB) v += bscale * bias[cn];
                if constexpr (RELU) v = fmaxf(v, 0.f);
                Cp[(long)cm * ldc + cn] = v;
            }
        }
    }
}

// ---------------------------------------------------------------------------
// Cooperative mega-kernel: whole pipeline, 5 stages, 4 grid syncs.
// Stage A: adj reduction (9216 units) || R = X@[W0|W1a|Wout]^T (912 units)
// Stage B: G0 = relu(A0@P0 + P0 + 2 b0)                       (240 units)
// Stage C: s12 (384) || P1 += G0@W1b^T (240) || out = G0@WoutL^T+R3+bout (480)
// Stage D: G1 = relu(A1@P1 + P1 + 2 b1), A1 fused              (240 units)
// Stage E: out += G1@WoutR^T                                   (480 units)
// ---------------------------------------------------------------------------
__global__ __launch_bounds__(256, 4)
void mega(const float* __restrict__ adj, const float* __restrict__ X,
          const float* __restrict__ W0, const float* __restrict__ b0,
          const float* __restrict__ W1, const float* __restrict__ b1,
          const float* __restrict__ Wh, const float* __restrict__ bh,
          const float* __restrict__ Wout, const float* __restrict__ bout,
          float* __restrict__ sm, float* __restrict__ A0,
          float* __restrict__ wadj, float* __restrict__ R,
          float* __restrict__ Gbuf, float* __restrict__ s12,
          float* __restrict__ out)
{
    // LDS union: reduce tile (13056 B) + wec (256 B)  >=  GEMM As/Bs (9216 B)
    __shared__ float ldsf[64 * 51 + 64];
    short* As   = (short*)ldsf;
    short* Bs   = As + 32 * 72;
    float* tile = ldsf;
    float* wec  = ldsf + 64 * 51;

    const int bid = blockIdx.x, nb = gridDim.x;
    const int t = threadIdx.x;

    // per-block we-colsums (tiny, all L1/L2 hits); block 0 materializes sm[]
    if (t < Ec) {
        float s = 0.f;
        for (int e = 0; e < Ec; ++e) s += Wh[e * WHC + t];
        wec[t] = s;
    }
    if (bid == 0) {
        for (int u = t; u < 512; u += 256) {
            if (u < Ec) {
                float s = 0.f;
                for (int e = 0; e < Ec; ++e) s += Wh[e*WHC + u];
                sm[u] = s;
            } else if (u >= 64 && u < 64 + HDc) {
                int h = u - 64; float s = 0.f;
                for (int e = 0; e < Ec; ++e) s += Wh[e*WHC + Ec + h];
                sm[u] = s;
            } else if (u >= 224 && u < 224 + HDc) {
                int h = u - 224; float s = 0.f;
                for (int e = 0; e < Ec; ++e) s += Wh[e*WHC + Ec + HDc + h];
                sm[u] = s;
            } else if (u == 384) {
                float s = 0.f;
                for (int e = 0; e < Ec; ++e) s += bh[e];
                sm[u] = s;
            }
        }
    }
    __syncthreads();

    const long AS = (long)Sc * Sc;
    const long RS = (long)Sc * 600;
    const long GS = (long)Sc * Dc;

    cg::grid_group grid = cg::this_grid();

    // ---- Stage A ----------------------------------------------------------
    {
        const int UR = (Bc * Sc * Sc) / 64;     // 9216 reduce units
        const int UT = UR + 19 * 48;            // + 912 gemm3 units
        for (int u = bid; u < UT; u += nb) {
            if (u < UR) {
                reduce_unit(tile, wec, adj, A0, wadj, u);
            } else {
                int v = u - UR;
                mgemm_body<2,0,0,0,0>(As, Bs, v % 19, v / 19, 0,
                    X, Dc, 0, W0, 300, 0, W1, Wout,
                    nullptr, 0, 0, nullptr, 0.f, nullptr, nullptr,
                    R, 600, 0, MT, 600, Dc);
            }
        }
    }
    grid.sync();

    // ---- Stage B ----------------------------------------------------------
    for (int u = bid; u < 5 * 12 * Bc; u += nb) {
        mgemm_body<0,0,1,1,1>(As, Bs, u % 5, (u / 5) % 12, u / 60,
            A0, Sc, AS, R, 600, RS, nullptr, nullptr,
            R, 600, RS, b0, 2.0f, nullptr, nullptr,
            Gbuf, Dc, GS, Sc, HDc, Sc);
    }
    grid.sync();

    // ---- Stage C ----------------------------------------------------------
    {
        const int U1 = MT / 4;            // 384 s12 units
        const int U2 = U1 + 5 * 48;       // + 240 gemm6 units
        const int U3 = U2 + 10 * 48;      // + 480 gemm8a units
        for (int u = bid; u < U3; u += nb) {
            if (u < U1) {
                s12_unit(Gbuf, sm, s12, u);
            } else if (u < U2) {
                int v = u - U1;
                mgemm_body<1,0,1,0,0>(As, Bs, v % 5, v / 5, 0,
                    Gbuf, Dc, 0, W1 + Dc, Dc + HDc, 0, nullptr, nullptr,
                    R + HDc, 600, 0, nullptr, 0.f, nullptr, nullptr,
                    R + HDc, 600, 0, MT, HDc, HDc);
            } else {
                int v = u - U2;
                mgemm_body<1,0,1,1,0>(As, Bs, v % 10, v / 10, 0,
                    Gbuf, Dc, 0, Wout, Dc, 0, nullptr, nullptr,
                    R + 2 * HDc, 600, 0, bout, 1.0f, nullptr, nullptr,
                    out, Dc, 0, MT, Dc, HDc);
            }
        }
    }
    grid.sync();

    // ---- Stage D ----------------------------------------------------------
    for (int u = bid; u < 5 * 12 * Bc; u += nb) {
        mgemm_body<0,1,1,1,1>(As, Bs, u % 5, (u / 5) % 12, u / 60,
            wadj, Sc, AS, R + HDc, 600, RS, nullptr, nullptr,
            R + HDc, 600, RS, b1, 2.0f, s12, sm,
            Gbuf + HDc, Dc, GS, Sc, HDc, Sc);
    }
    grid.sync();

    // ---- Stage E ----------------------------------------------------------
    for (int u = bid; u < 10 * 48; u += nb) {
        mgemm_body<1,0,1,0,0>(As, Bs, u % 10, u / 10, 0,
            Gbuf + HDc, Dc, 0, Wout + HDc, Dc, 0, nullptr, nullptr,
            out, Dc, 0, nullptr, 0.f, nullptr, nullptr,
            out, Dc, 0, MT, Dc, HDc);
    }
}

// ---------------------------------------------------------------------------
// Fallback path: original 8-kernel chain (used only if cooperative launch
// is rejected by the runtime/capture). Same device bodies.
// ---------------------------------------------------------------------------
__global__ void prep_kernel(const float* __restrict__ Wh,
                            const float* __restrict__ bh,
                            float* __restrict__ sm) {
    int t = threadIdx.x;  // 512 threads
    if (t < Ec) {
        float s = 0.f;
        for (int e = 0; e < Ec; ++e) s += Wh[e*WHC + t];
        sm[t] = s;
    } else if (t >= 64 && t < 64 + HDc) {
        int h = t - 64;
        float s = 0.f;
        for (int e = 0; e < Ec; ++e) s += Wh[e*WHC + Ec + h];
        sm[t] = s;
    } else if (t >= 224 && t < 224 + HDc) {
        int h = t - 224;
        float s = 0.f;
        for (int e = 0; e < Ec; ++e) s += Wh[e*WHC + Ec + HDc + h];
        sm[t] = s;
    } else if (t == 384) {
        float s = 0.f;
        for (int e = 0; e < Ec; ++e) s += bh[e];
        sm[t] = s;
    }
}

__global__ __launch_bounds__(256)
void reduce_adj3(const float* __restrict__ adj, const float* __restrict__ sm,
                 float* __restrict__ A0, float* __restrict__ wadj) {
    __shared__ float lds[64 * 51 + 64];
    float* tile = lds;
    float* wec  = lds + 64 * 51;
    if (threadIdx.x < Ec) wec[threadIdx.x] = sm[threadIdx.x];
    reduce_unit(tile, wec, adj, A0, wadj, blockIdx.x);
}

template<int BSRC, int A1M, int HASD, int HASB, int RELU>
__global__ __launch_bounds__(256)
void mgemm(const float* __restrict__ A, int lda, long sA,
           const float* __restrict__ Bw, int ldb, long sB,
           const float* __restrict__ W1a, const float* __restrict__ WoutP,
           const float* __restrict__ Dm, int ldd, long sD,
           const float* __restrict__ bias, float bscale,
           const float* __restrict__ s12, const float* __restrict__ sm,
           float* __restrict__ C, int ldc, long sC,
           int M, int N, int K)
{
    __shared__ short As[32 * 72];
    __shared__ short Bs[32 * 72];
    mgemm_body<BSRC,A1M,HASD,HASB,RELU>(As, Bs,
        blockIdx.x, blockIdx.y, blockIdx.z,
        A, lda, sA, Bw, ldb, sB, W1a, WoutP, Dm, ldd, sD,
        bias, bscale, s12, sm, C, ldc, sC, M, N, K);
}

__global__ __launch_bounds__(256)
void s12k(const float* __restrict__ G, const float* __restrict__ sm,
          float* __restrict__ s12) {
    s12_unit(G, sm, s12, blockIdx.x);
}

extern "C" void kernel_launch(void* const* d_in, const int* in_sizes, int n_in,
                              void* d_out, int out_size, void* d_ws, size_t ws_size,
                              hipStream_t stream) {
    const float* adj  = (const float*)d_in[0];
    const float* X    = (const float*)d_in[1];
    const float* W0   = (const float*)d_in[2];
    const float* b0   = (const float*)d_in[3];
    const float* W1   = (const float*)d_in[4];
    const float* b1   = (const float*)d_in[5];
    const float* Wh   = (const float*)d_in[6];
    const float* bh   = (const float*)d_in[7];
    const float* Wout = (const float*)d_in[8];
    const float* bout = (const float*)d_in[9];
    float* out = (float*)d_out;

    // workspace layout (floats)
    float* ws   = (float*)d_ws;
    float* sm   = ws;                          // 512
    float* A0   = sm + 512;                    // 1536 x 384
    float* wadj = A0 + Bc * Sc * Sc;           // 1536 x 384
    float* R    = wadj + Bc * Sc * Sc;         // 1536 x 600: [P0 | P1 | X@Wout^T]
    float* Gbuf = R + (long)Bc * Sc * 600;     // 1536 x 300: [G0 | G1]
    float* s12  = Gbuf + (long)Bc * Sc * Dc;   // 1536 x 2 interleaved

    const long AS = (long)Sc * Sc;
    const long RS = (long)Sc * 600;
    const long GS = (long)Sc * Dc;

    // Grid size: co-resident capacity (cached). Grid-stride loops make any
    // grid size correct; cooperative launch validates residency for us.
    static int grid_size = 0;
    if (grid_size == 0) {
        int nbm = 0;
        if (hipOccupancyMaxActiveBlocksPerMultiprocessor(&nbm, mega, 256, 0) != hipSuccess || nbm < 1)
            nbm = 2;
        int ncu = 256;
        hipDeviceProp_t prop;
        int dev = 0;
        (void)hipGetDevice(&dev);
        if (hipGetDeviceProperties(&prop, dev) == hipSuccess && prop.multiProcessorCount > 0)
            ncu = prop.multiProcessorCount;
        long g = (long)nbm * ncu;
        if (g > 1024) g = 1024;
        if (g < 256)  g = 256;
        grid_size = (int)g;
    }

    void* args[] = {
        (void*)&adj, (void*)&X, (void*)&W0, (void*)&b0, (void*)&W1, (void*)&b1,
        (void*)&Wh, (void*)&bh, (void*)&Wout, (void*)&bout,
        (void*)&sm, (void*)&A0, (void*)&wadj, (void*)&R, (void*)&Gbuf,
        (void*)&s12, (void*)&out
    };

    hipError_t err = hipLaunchCooperativeKernel(mega, dim3(grid_size), dim3(256),
                                                args, 0u, stream);
    if (err != hipSuccess) {
        // -------- fallback: original verified 8-kernel chain --------
        const int MT_ = MT;
        prep_kernel<<<1, 512, 0, stream>>>(Wh, bh, sm);
        reduce_adj3<<<(Bc*Sc*Sc) / 64, 256, 0, stream>>>(adj, sm, A0, wadj);
        mgemm<2,0,0,0,0><<<dim3(19, 48, 1), 256, 0, stream>>>(
            X, Dc, 0, W0, 300, 0, W1, Wout,
            nullptr, 0, 0, nullptr, 0.f, nullptr, nullptr,
            R, 600, 0, MT_, 600, Dc);
        mgemm<0,0,1,1,1><<<dim3(5, 12, Bc), 256, 0, stream>>>(
            A0, Sc, AS, R, 600, RS, nullptr, nullptr,
            R, 600, RS, b0, 2.0f, nullptr, nullptr,
            Gbuf, Dc, GS, Sc, HDc, Sc);
        s12k<<<MT_ / 4, 256, 0, stream>>>(Gbuf, sm, s12);
        mgemm<1,0,1,0,0><<<dim3(5, 48, 1), 256, 0, stream>>>(
            Gbuf, Dc, 0, W1 + Dc, Dc + HDc, 0, nullptr, nullptr,
            R + HDc, 600, 0, nullptr, 0.f, nullptr, nullptr,
            R + HDc, 600, 0, MT_, HDc, HDc);
        mgemm<0,1,1,1,1><<<dim3(5, 12, Bc), 256, 0, stream>>>(
            wadj, Sc, AS, R + HDc, 600, RS, nullptr, nullptr,
            R + HDc, 600, RS, b1, 2.0f, s12, sm,
            Gbuf + HDc, Dc, GS, Sc, HDc, Sc);
        mgemm<1,0,1,1,0><<<dim3(10, 48, 1), 256, 0, stream>>>(
            Gbuf, Dc, 0, Wout, Dc, 0, nullptr, nullptr,
            R + 2*HDc, 600, 0, bout, 1.0f, nullptr, nullptr,
            out, Dc, 0, MT_, Dc, Dc);
    }
}

// Round 2
// 227.190 us; speedup vs baseline: 2.1656x; 2.1656x over previous
//
#include <hip/hip_runtime.h>

// Problem constants
constexpr int Bc  = 4;
constexpr int Sc  = 384;
constexpr int Dc  = 300;
constexpr int Ec  = 50;
constexpr int HDc = 150;          // D / L
constexpr int WHC = 350;          // Wh row length
constexpr int MT  = Bc * Sc;      // 1536

typedef __attribute__((ext_vector_type(8))) short bf16x8;
typedef __attribute__((ext_vector_type(4))) float f32x4;

__device__ __forceinline__ short f2bf(float x) {
    union { float f; unsigned u; } v; v.f = x;
    unsigned r = (v.u + 0x7FFFu + ((v.u >> 16) & 1u)) >> 16;
    return (short)r;
}

// ---------------------------------------------------------------------------
// s12 unit: wave per row. s12[2g] = G0[g]·w1cs, s12[2g+1] = G0[g]·w2cs
// ---------------------------------------------------------------------------
__device__ __forceinline__ void s12_unit(const float* __restrict__ G,
                                         const float* __restrict__ sm,
                                         float* __restrict__ s12, int unit)
{
    int wave = threadIdx.x >> 6, lane = threadIdx.x & 63;
    int g = unit * 4 + wave;
    const float* gp = G + (long)g * Dc;
    float a = 0.f, c = 0.f;
    #pragma unroll
    for (int h0 = 0; h0 < HDc; h0 += 64) {
        int h = h0 + lane;
        if (h < HDc) { float v = gp[h]; a += v * sm[64 + h]; c += v * sm[224 + h]; }
    }
    #pragma unroll
    for (int off = 32; off; off >>= 1) {
        a += __shfl_down(a, off);
        c += __shfl_down(c, off);
    }
    if (lane == 0) { s12[2*g] = a; s12[2*g + 1] = c; }
}

// ---------------------------------------------------------------------------
// bf16 MFMA GEMM body, 256 thr = 4 waves, 32x32 C tile, BK=64 (two
// mfma_f32_16x16x32_bf16 per wave per iter), fp32->bf16 fused into LDS
// staging, register-prefetch double buffer. LDS row stride 72 shorts.
// BSRC 0: B k-major (ld ldb, batched sB). 1: B row-major N x K (ld ldb).
// 2: B = concat [W0 | W1[:,0:300] | Wout] row-major, K=300.
// A1M: A element = (wadj + s1[k] + s2[m] + sbh)/E from s12/sm
// ---------------------------------------------------------------------------
template<int BSRC, int A1M, int HASD, int HASB, int RELU>
__device__ __forceinline__ void mgemm_body(
    short* As, short* Bs, int bx, int by, int b,
    const float* __restrict__ A, int lda, long sA,
    const float* __restrict__ Bw, int ldb, long sB,
    const float* __restrict__ W1a, const float* __restrict__ WoutP,
    const float* __restrict__ Dm, int ldd, long sD,
    const float* __restrict__ bias, float bscale,
    const float* __restrict__ s12, const float* __restrict__ sm,
    float* __restrict__ C, int ldc, long sC,
    int M, int N, int K)
{
    const float* Ap = A + (long)b * sA;
    const float* Bp = Bw + (long)b * sB;
    const float* Dp = Dm + (long)b * sD;
    float* Cp = C + (long)b * sC;

    const int tid  = threadIdx.x;
    const int wave = tid >> 6, lane = tid & 63;
    const int wm = wave & 1, wn = wave >> 1;
    const int lm = lane & 15, quad = lane >> 4;
    const int m0 = by * 32, n0 = bx * 32;

    const int srow = tid >> 3;           // 0..31 (A rows / B n-rows)
    const int sk   = (tid & 7) * 8;      // 0,8,..,56
    const int nc   = tid & 31;           // BSRC0 n
    const int kr   = tid >> 5;           // BSRC0 k base 0..7

    float sbh = 0.f; const float* s1p = nullptr; float s2v = 0.f;
    if constexpr (A1M) {
        sbh = sm[384];
        s1p = s12 + 2L * Sc * b;
        s2v = s1p[2 * (m0 + srow) + 1];
    }

    float ra[8], rb[8];

    auto stageA = [&](int k0) {
        int am = m0 + srow;
        int kb = k0 + sk;
        if constexpr (A1M) {             // K=384 exact, no masks
            float4 u = *(const float4*)(Ap + (long)am * lda + kb);
            float4 w = *(const float4*)(Ap + (long)am * lda + kb + 4);
            const float* up = (const float*)&u;
            const float* wp = (const float*)&w;
            #pragma unroll
            for (int j = 0; j < 4; ++j) {
                ra[j]     = (up[j] + s1p[2*(kb + j)]     + s2v + sbh) * (1.0f/Ec);
                ra[4 + j] = (wp[j] + s1p[2*(kb + 4 + j)] + s2v + sbh) * (1.0f/Ec);
            }
        } else {
            if (kb + 7 < K) {
                float4 u = *(const float4*)(Ap + (long)am * lda + kb);
                float4 w = *(const float4*)(Ap + (long)am * lda + kb + 4);
                ra[0]=u.x; ra[1]=u.y; ra[2]=u.z; ra[3]=u.w;
                ra[4]=w.x; ra[5]=w.y; ra[6]=w.z; ra[7]=w.w;
            } else {
                #pragma unroll
                for (int j = 0; j < 8; ++j) {
                    int k = kb + j;
                    ra[j] = (k < K) ? Ap[(long)am * lda + k] : 0.f;
                }
            }
        }
    };

    auto stageB = [&](int k0) {
        if constexpr (BSRC == 0) {       // k-major, K=384 exact here
            int n = n0 + nc;
            bool nok = n < N;
            #pragma unroll
            for (int p = 0; p < 8; ++p) {
                int k = k0 + kr + p * 8;
                rb[p] = nok ? Bp[(long)k * ldb + n] : 0.f;
            }
        } else {
            int nr = n0 + srow;
            bool nok = nr < N;
            const float* wp = Bp; int ld = ldb; int nn = nr;
            if constexpr (BSRC == 2) {
                if (nr < 150)      { wp = Bp;    ld = 300; nn = nr; }
                else if (nr < 300) { wp = W1a;   ld = 450; nn = nr - 150; }
                else               { wp = WoutP; ld = 300; nn = nr - 300; }
            }
            #pragma unroll
            for (int p = 0; p < 4; ++p) {
                int k = k0 + sk + 2 * p;
                if (nok && k + 1 < K) {
                    float2 v = *(const float2*)(wp + (long)nn * ld + k);
                    rb[2*p] = v.x; rb[2*p + 1] = v.y;
                } else {
                    rb[2*p]     = (nok && k < K)     ? wp[(long)nn * ld + k]     : 0.f;
                    rb[2*p + 1] = (nok && k + 1 < K) ? wp[(long)nn * ld + k + 1] : 0.f;
                }
            }
        }
    };

    auto stash = [&]() {
        #pragma unroll
        for (int j = 0; j < 8; ++j) As[srow * 72 + sk + j] = f2bf(ra[j]);
        if constexpr (BSRC == 0) {
            #pragma unroll
            for (int p = 0; p < 8; ++p) Bs[nc * 72 + kr + p * 8] = f2bf(rb[p]);
        } else {
            #pragma unroll
            for (int j = 0; j < 8; ++j) Bs[srow * 72 + sk + j] = f2bf(rb[j]);
        }
    };

    f32x4 acc = {0.f, 0.f, 0.f, 0.f};

    stageA(0); stageB(0);
    for (int k0 = 0; k0 < K; k0 += 64) {
        __syncthreads();
        stash();
        __syncthreads();
        if (k0 + 64 < K) { stageA(k0 + 64); stageB(k0 + 64); }
        {
            bf16x8 a0 = *(const bf16x8*)(As + (wm*16 + lm) * 72 + quad * 8);
            bf16x8 b0 = *(const bf16x8*)(Bs + (wn*16 + lm) * 72 + quad * 8);
            acc = __builtin_amdgcn_mfma_f32_16x16x32_bf16(a0, b0, acc, 0, 0, 0);
            bf16x8 a1 = *(const bf16x8*)(As + (wm*16 + lm) * 72 + 32 + quad * 8);
            bf16x8 b1 = *(const bf16x8*)(Bs + (wn*16 + lm) * 72 + 32 + quad * 8);
            acc = __builtin_amdgcn_mfma_f32_16x16x32_bf16(a1, b1, acc, 0, 0, 0);
        }
    }

    int cn = n0 + wn * 16 + lm;
    if (cn < N) {
        #pragma unroll
        for (int r = 0; r < 4; ++r) {
            int cm = m0 + wm * 16 + quad * 4 + r;
            if (cm < M) {
                float v = acc[r];
                if constexpr (HASD) v += Dp[(long)cm * ldd + cn];
                if constexpr (HASB) v += bscale * bias[cn];
                if constexpr (RELU) v = fmaxf(v, 0.f);
                Cp[(long)cm * ldc + cn] = v;
            }
        }
    }
}

// standalone GEMM launcher (D2, D4, D5)
template<int BSRC, int A1M, int HASD, int HASB, int RELU>
__global__ __launch_bounds__(256)
void mgemm(const float* __restrict__ A, int lda, long sA,
           const float* __restrict__ Bw, int ldb, long sB,
           const float* __restrict__ W1a, const float* __restrict__ WoutP,
           const float* __restrict__ Dm, int ldd, long sD,
           const float* __restrict__ bias, float bscale,
           const float* __restrict__ s12, const float* __restrict__ sm,
           float* __restrict__ C, int ldc, long sC,
           int M, int N, int K)
{
    __shared__ short As[32 * 72];
    __shared__ short Bs[32 * 72];
    mgemm_body<BSRC,A1M,HASD,HASB,RELU>(As, Bs,
        blockIdx.x, blockIdx.y, blockIdx.z,
        A, lda, sA, Bw, ldb, sB, W1a, WoutP, Dm, ldd, sD,
        bias, bscale, s12, sm, C, ldc, sC, M, N, K);
}

// ---------------------------------------------------------------------------
// D1: gemm3 (912 blocks) + sm prep (1 block) + adj reduction (9216 blocks).
// Reduce blocks compute wec (Wh col-sums, L2-resident) UNDER the in-flight
// adj loads -> no separate prep dependency. LDS union, 13.3 KB.
// ---------------------------------------------------------------------------
__global__ __launch_bounds__(256)
void fused1(const float* __restrict__ adj, const float* __restrict__ X,
            const float* __restrict__ W0, const float* __restrict__ W1,
            const float* __restrict__ Wout, const float* __restrict__ Wh,
            const float* __restrict__ bh,
            float* __restrict__ sm, float* __restrict__ A0,
            float* __restrict__ wadj, float* __restrict__ R)
{
    __shared__ float lds[64 * 51 + 64];      // 13312 B union
    const int bx = blockIdx.x, t = threadIdx.x;

    if (bx < 912) {
        // R = X @ [W0 | W1a | Wout]^T  (M=1536, N=600, K=300)
        short* As = (short*)lds;
        short* Bs = As + 32 * 72;
        mgemm_body<2,0,0,0,0>(As, Bs, bx % 19, bx / 19, 0,
            X, Dc, 0, W0, 300, 0, W1, Wout,
            nullptr, 0, 0, nullptr, 0.f, nullptr, nullptr,
            R, 600, 0, MT, 600, Dc);
    } else if (bx == 912) {
        // sm: [0..49] we, [64..213] w1, [224..373] w2, [384] sum(bh)
        for (int u = t; u < 512; u += 256) {
            if (u < Ec) {
                float s = 0.f;
                for (int e = 0; e < Ec; ++e) s += Wh[e*WHC + u];
                sm[u] = s;
            } else if (u >= 64 && u < 64 + HDc) {
                int h = u - 64; float s = 0.f;
                for (int e = 0; e < Ec; ++e) s += Wh[e*WHC + Ec + h];
                sm[u] = s;
            } else if (u >= 224 && u < 224 + HDc) {
                int h = u - 224; float s = 0.f;
                for (int e = 0; e < Ec; ++e) s += Wh[e*WHC + Ec + HDc + h];
                sm[u] = s;
            } else if (u == 384) {
                float s = 0.f;
                for (int e = 0; e < Ec; ++e) s += bh[e];
                sm[u] = s;
            }
        }
    } else {
        // 64-row adj tile: A0[g] = (sum_e adj[g,:])/E ; wadj[g] = sum adj*we
        const int unit = bx - 913;
        float* tile = lds;
        float* wec  = lds + 64 * 51;

        long base = (long)unit * 3200;       // 64 rows * 50 floats
        const float4* p4 = (const float4*)(adj + base);
        float4 v0 = p4[t];
        float4 v1 = p4[t + 256];
        float4 v2 = p4[t + 512];
        float4 v3 = {0.f, 0.f, 0.f, 0.f};
        if (t < 32) v3 = p4[t + 768];

        // Wh col-sums hide under the HBM loads above (Wh is L2-resident)
        if (t < Ec) {
            float s = 0.f;
            for (int e = 0; e < Ec; ++e) s += Wh[e * WHC + t];
            wec[t] = s;
        }

        auto scat = [&](int i, const float4& v) {
            const float* vp = (const float*)&v;
            #pragma unroll
            for (int j = 0; j < 4; ++j) {
                int e = 4 * i + j;
                tile[(e / 50) * 51 + (e % 50)] = vp[j];
            }
        };
        scat(t, v0);
        scat(t + 256, v1);
        scat(t + 512, v2);
        if (t < 32) scat(t + 768, v3);
        __syncthreads();

        int r = t >> 2, q = t & 3;
        int h0 = q * 13, h1 = (q == 3) ? 50 : h0 + 13;
        const float* row = tile + r * 51;
        float s = 0.f, w = 0.f;
        for (int i = h0; i < h1; ++i) { float v = row[i]; s += v; w += v * wec[i]; }
        s += __shfl_xor(s, 1); w += __shfl_xor(w, 1);
        s += __shfl_xor(s, 2); w += __shfl_xor(w, 2);
        if (q == 0) {
            int g = unit * 64 + r;
            A0[g]   = s * (1.0f / Ec);
            wadj[g] = w;
        }
    }
}

// ---------------------------------------------------------------------------
// D3: gemm8a (480) + gemm6 (240) + s12 (384) fused — all independent, all
// read G0. out = G0@WoutL^T + R3 + bout ; P1 = Q1 + G0@W1b^T ; s12 rows.
// ---------------------------------------------------------------------------
__global__ __launch_bounds__(256)
void fused3(const float* __restrict__ Gbuf, const float* __restrict__ sm,
            float* __restrict__ s12, const float* __restrict__ W1,
            float* __restrict__ R, const float* __restrict__ Wout,
            const float* __restrict__ bout, float* __restrict__ out)
{
    __shared__ short As[32 * 72];
    __shared__ short Bs[32 * 72];
    const int bx = blockIdx.x;

    if (bx < 480) {
        // out = G0 @ WoutL^T + R3 + bout  (M=1536, N=300, K=150)
        mgemm_body<1,0,1,1,0>(As, Bs, bx % 10, bx / 10, 0,
            Gbuf, Dc, 0, Wout, Dc, 0, nullptr, nullptr,
            R + 2 * HDc, 600, 0, bout, 1.0f, nullptr, nullptr,
            out, Dc, 0, MT, Dc, HDc);
    } else if (bx < 480 + 240) {
        // P1 = Q1 + G0 @ W1b^T  (M=1536, N=150, K=150; in-place R[:,150:300])
        int v = bx - 480;
        mgemm_body<1,0,1,0,0>(As, Bs, v % 5, v / 5, 0,
            Gbuf, Dc, 0, W1 + Dc, Dc + HDc, 0, nullptr, nullptr,
            R + HDc, 600, 0, nullptr, 0.f, nullptr, nullptr,
            R + HDc, 600, 0, MT, HDc, HDc);
    } else {
        s12_unit(Gbuf, sm, s12, bx - 720);
    }
}

extern "C" void kernel_launch(void* const* d_in, const int* in_sizes, int n_in,
                              void* d_out, int out_size, void* d_ws, size_t ws_size,
                              hipStream_t stream) {
    const float* adj  = (const float*)d_in[0];
    const float* X    = (const float*)d_in[1];
    const float* W0   = (const float*)d_in[2];
    const float* b0   = (const float*)d_in[3];
    const float* W1   = (const float*)d_in[4];
    const float* b1   = (const float*)d_in[5];
    const float* Wh   = (const float*)d_in[6];
    const float* bh   = (const float*)d_in[7];
    const float* Wout = (const float*)d_in[8];
    const float* bout = (const float*)d_in[9];
    float* out = (float*)d_out;

    // workspace layout (floats)
    float* ws   = (float*)d_ws;
    float* sm   = ws;                          // 512
    float* A0   = sm + 512;                    // 1536 x 384
    float* wadj = A0 + Bc * Sc * Sc;           // 1536 x 384
    float* R    = wadj + Bc * Sc * Sc;         // 1536 x 600: [P0 | P1 | X@Wout^T]
    float* Gbuf = R + (long)Bc * Sc * 600;     // 1536 x 300: [G0 | G1]
    float* s12  = Gbuf + (long)Bc * Sc * Dc;   // 1536 x 2 interleaved

    const long AS = (long)Sc * Sc;             // adj batch stride
    const long RS = (long)Sc * 600;            // R batch stride (rows)
    const long GS = (long)Sc * Dc;             // Gbuf batch stride

    // D1: gemm3 + sm + adj reduction  (912 + 1 + 9216 blocks)
    fused1<<<912 + 1 + (Bc*Sc*Sc)/64, 256, 0, stream>>>(
        adj, X, W0, W1, Wout, Wh, bh, sm, A0, wadj, R);

    // D2: G0 = relu(A0 @ P0 + P0 + 2*b0)  (batched; M=384, N=150, K=384)
    mgemm<0,0,1,1,1><<<dim3(5, 12, Bc), 256, 0, stream>>>(
        A0, Sc, AS, R, 600, RS, nullptr, nullptr,
        R, 600, RS, b0, 2.0f, nullptr, nullptr,
        Gbuf, Dc, GS, Sc, HDc, Sc);

    // D3: gemm8a + gemm6 + s12  (480 + 240 + 384 blocks)
    fused3<<<480 + 240 + 384, 256, 0, stream>>>(
        Gbuf, sm, s12, W1, R, Wout, bout, out);

    // D4: G1 = relu(A1 @ P1 + P1 + 2*b1); A1 fused from wadj+s12 (batched)
    mgemm<0,1,1,1,1><<<dim3(5, 12, Bc), 256, 0, stream>>>(
        wadj, Sc, AS, R + HDc, 600, RS, nullptr, nullptr,
        R + HDc, 600, RS, b1, 2.0f, s12, sm,
        Gbuf + HDc, Dc, GS, Sc, HDc, Sc);

    // D5: out += G1 @ WoutR^T  (M=1536, N=300, K=150)
    mgemm<1,0,1,0,0><<<dim3(10, 48, 1), 256, 0, stream>>>(
        Gbuf + HDc, Dc, 0, Wout + HDc, Dc, 0, nullptr, nullptr,
        out, Dc, 0, nullptr, 0.f, nullptr, nullptr,
        out, Dc, 0, MT, Dc, HDc);
}